// Round 2
// baseline (59.780 us; speedup 1.0000x reference)
//
#include <hip/hip_runtime.h>
#include <hip/hip_bf16.h>
#include <math.h>

#define CDIM 2048
#define EDIM 64
#define BM   32
#define BK   64
#define LDA  72   // fp16 elems per LDS row (64 + 8 pad -> 144B, 16B aligned)
#define LDB  72

// scales keep fp16 "lo" parts in normal range; product scale = 2^22
#define SCALE_H 1024.0f
#define SCALE_W 4096.0f
#define INV_SCALE (1.0f / 4194304.0f)

typedef float    f32x16 __attribute__((ext_vector_type(16)));
typedef _Float16 f16x8  __attribute__((ext_vector_type(8)));

__device__ __forceinline__ unsigned short f2h_bits(float f) {
    _Float16 h = (_Float16)f;                       // v_cvt_f16_f32, RTN
    return __builtin_bit_cast(unsigned short, h);
}
__device__ __forceinline__ float h2f(unsigned short b) {
    return (float)__builtin_bit_cast(_Float16, b);
}

// ---- prep: column-normalize sim_matrix, scale by 2^12, split to fp16 hi/lo, store transposed [E][C]
__global__ void prep_w(const float* __restrict__ W,
                       unsigned short* __restrict__ whi,
                       unsigned short* __restrict__ wlo) {
    int e = blockIdx.x, t = threadIdx.x;
    float s = 0.f;
    for (int c = t; c < CDIM; c += 256) {
        float v = W[(size_t)c * EDIM + e];
        s += v * v;
    }
    __shared__ float red[256];
    red[t] = s;
    __syncthreads();
    for (int off = 128; off > 0; off >>= 1) {
        if (t < off) red[t] += red[t + off];
        __syncthreads();
    }
    float inv = SCALE_W / fmaxf(sqrtf(red[0]), 1e-12f);
    for (int c = t; c < CDIM; c += 256) {
        float v = W[(size_t)c * EDIM + e] * inv;
        unsigned short hb = f2h_bits(v);
        whi[(size_t)e * CDIM + c] = hb;
        wlo[(size_t)e * CDIM + c] = f2h_bits(v - h2f(hb));
    }
}

// ---- main: fused normalize + GEMM (split-fp16 MFMA, 3 chains) + gating epilogue
__launch_bounds__(128, 2)
__global__ void gating_main(const float* __restrict__ H,
                            const unsigned short* __restrict__ whi,
                            const unsigned short* __restrict__ wlo,
                            const float* __restrict__ gates,
                            float* __restrict__ out_rw,
                            float* __restrict__ out_lg,
                            float* __restrict__ out_mk) {
    __shared__ unsigned short a_hi[BM][LDA], a_lo[BM][LDA];
    __shared__ unsigned short b_hi[EDIM][LDB], b_lo[EDIM][LDB];
    __shared__ float logit_s[BM][EDIM + 4];
    __shared__ float inv_hn[BM];
    __shared__ float sig_s[EDIM];

    const int t = threadIdx.x;            // 0..127
    const int row0 = blockIdx.x * BM;
    const int lane = t & 63;
    const int wv = t >> 6;                // wave id: n-tile 0/1
    const int arow = lane & 31;
    const int kg = lane >> 5;
    const int bcol = wv * 32 + arow;      // expert column

    if (t < EDIM) sig_s[t] = 1.f / (1.f + expf(-gates[t]));

    f32x16 acc_hh, acc_hl, acc_lh;
#pragma unroll
    for (int i = 0; i < 16; i++) { acc_hh[i] = 0.f; acc_hl[i] = 0.f; acc_lh[i] = 0.f; }

    const int srow = t >> 2;              // staging row 0..31
    const int cseg = t & 3;               // 16-float segment
    float nacc = 0.f;

    for (int k0 = 0; k0 < CDIM; k0 += BK) {
        // ---- stage A: 32 rows x 64 k of fp32 h -> fp16 hi/lo (scaled), fused norm accum
        {
            const float4* g = reinterpret_cast<const float4*>(
                H + (size_t)(row0 + srow) * CDIM + k0 + cseg * 16);
            float vv[16];
#pragma unroll
            for (int i = 0; i < 4; i++) {
                float4 f = g[i];
                vv[i * 4 + 0] = f.x; vv[i * 4 + 1] = f.y;
                vv[i * 4 + 2] = f.z; vv[i * 4 + 3] = f.w;
            }
            unsigned int hw[8], lw[8];
#pragma unroll
            for (int j = 0; j < 16; j++) {
                float v = vv[j];
                nacc += v * v;
                float vs = v * SCALE_H;
                unsigned short hb = f2h_bits(vs);
                unsigned short lb = f2h_bits(vs - h2f(hb));
                if (j & 1) { hw[j >> 1] |= ((unsigned int)hb) << 16; lw[j >> 1] |= ((unsigned int)lb) << 16; }
                else       { hw[j >> 1] = hb;                        lw[j >> 1] = lb; }
            }
            uint4* da = reinterpret_cast<uint4*>(&a_hi[srow][cseg * 16]);
            uint4* dl = reinterpret_cast<uint4*>(&a_lo[srow][cseg * 16]);
            da[0] = make_uint4(hw[0], hw[1], hw[2], hw[3]);
            da[1] = make_uint4(hw[4], hw[5], hw[6], hw[7]);
            dl[0] = make_uint4(lw[0], lw[1], lw[2], lw[3]);
            dl[1] = make_uint4(lw[4], lw[5], lw[6], lw[7]);
        }
        // ---- stage B: 64 experts x 64 k fp16 hi/lo from precomputed transposed W
        {
            int e = t >> 1, hseg = t & 1;
            const uint4* gh = reinterpret_cast<const uint4*>(whi + (size_t)e * CDIM + k0 + hseg * 32);
            const uint4* gl = reinterpret_cast<const uint4*>(wlo + (size_t)e * CDIM + k0 + hseg * 32);
            uint4* dh = reinterpret_cast<uint4*>(&b_hi[e][hseg * 32]);
            uint4* dl = reinterpret_cast<uint4*>(&b_lo[e][hseg * 32]);
#pragma unroll
            for (int i = 0; i < 4; i++) { dh[i] = gh[i]; dl[i] = gl[i]; }
        }
        __syncthreads();
        // ---- MFMA: 4 k-frags x 3 chains (hh, hl, lh; ll term ~2^-24 rel, negligible)
#pragma unroll
        for (int kk = 0; kk < 4; kk++) {
            f16x8 ah = *reinterpret_cast<const f16x8*>(&a_hi[arow][kk * 16 + kg * 8]);
            f16x8 al = *reinterpret_cast<const f16x8*>(&a_lo[arow][kk * 16 + kg * 8]);
            f16x8 bh = *reinterpret_cast<const f16x8*>(&b_hi[bcol][kk * 16 + kg * 8]);
            f16x8 bl = *reinterpret_cast<const f16x8*>(&b_lo[bcol][kk * 16 + kg * 8]);
            acc_hh = __builtin_amdgcn_mfma_f32_32x32x16_f16(ah, bh, acc_hh, 0, 0, 0);
            acc_hl = __builtin_amdgcn_mfma_f32_32x32x16_f16(ah, bl, acc_hl, 0, 0, 0);
            acc_lh = __builtin_amdgcn_mfma_f32_32x32x16_f16(al, bh, acc_lh, 0, 0, 0);
        }
        __syncthreads();
    }

    // ---- row norms: 4 threads per row hold partials; fold 2^-22 product scale in
    nacc += __shfl_xor(nacc, 1);
    nacc += __shfl_xor(nacc, 2);
    if ((t & 3) == 0) inv_hn[srow] = INV_SCALE / fmaxf(sqrtf(nacc), 1e-12f);
    __syncthreads();

    // ---- epilogue: accumulators -> logits (write global + LDS)
    {
        float sg = sig_s[bcol];
#pragma unroll
        for (int r = 0; r < 16; r++) {
            int rowl = (r & 3) + 8 * (r >> 2) + 4 * (lane >> 5);
            float lg = (acc_hh[r] + acc_hl[r] + acc_lh[r]) * inv_hn[rowl] - sg;
            logit_s[rowl][bcol] = lg;
            out_lg[(size_t)(row0 + rowl) * EDIM + bcol] = lg;
        }
    }
    __syncthreads();

    // ---- per-row gating: 4 threads per row, 16 experts each
    {
        const int rr = t >> 2;
        const int e0 = (t & 3) * 16;
        float v1 = -INFINITY, v2 = -INFINITY;
        int i1 = 0x7fffffff, i2 = 0x7fffffff;
        int cnt = 0;
#pragma unroll
        for (int j = 0; j < 16; j++) {
            int e = e0 + j;
            float v = logit_s[rr][e];
            cnt += (v > 0.f) ? 1 : 0;
            if (v > v1) { v2 = v1; i2 = i1; v1 = v; i1 = e; }
            else if (v > v2) { v2 = v; i2 = e; }
        }
#pragma unroll
        for (int st = 1; st <= 2; st <<= 1) {
            float w1 = __shfl_xor(v1, st);
            int   j1 = __shfl_xor(i1, st);
            float w2 = __shfl_xor(v2, st);
            int   j2 = __shfl_xor(i2, st);
            int   cc = __shfl_xor(cnt, st);
            cnt += cc;
            bool g = (w1 > v1) || (w1 == v1 && j1 < i1);
            if (g) {
                bool g2 = (v1 > w2) || (v1 == w2 && i1 < j2);
                float nv2 = g2 ? v1 : w2;
                int   ni2 = g2 ? i1 : j2;
                v1 = w1; i1 = j1; v2 = nv2; i2 = ni2;
            } else {
                bool g2 = (w1 > v2) || (w1 == v2 && j1 < i2);
                if (g2) { v2 = w1; i2 = j1; }
            }
        }
        bool act = cnt > 0;
        float rmax = act ? v1 : 0.f;
        float xs[16], ms[16];
        float wsum = 0.f;
#pragma unroll
        for (int j = 0; j < 16; j++) {
            int e = e0 + j;
            float l = logit_s[rr][e];
            float x, m;
            if (act) {
                bool sel = l > 0.f;
                m = sel ? 1.f : 0.f;
                x = sel ? __expf(l - rmax) : 0.f;
            } else {
                bool sel = (e == i1) || (e == i2);
                m = sel ? 1.f : 0.f;
                x = m;
            }
            xs[j] = x; ms[j] = m; wsum += x;
        }
        wsum += __shfl_xor(wsum, 1);
        wsum += __shfl_xor(wsum, 2);
        float invd = 1.f / wsum;
        float* prw = out_rw + (size_t)(row0 + rr) * EDIM + e0;
        float* pmk = out_mk + (size_t)(row0 + rr) * EDIM + e0;
#pragma unroll
        for (int q = 0; q < 4; q++) {
            float4 rq = make_float4(xs[q * 4] * invd, xs[q * 4 + 1] * invd,
                                    xs[q * 4 + 2] * invd, xs[q * 4 + 3] * invd);
            float4 mq = make_float4(ms[q * 4], ms[q * 4 + 1], ms[q * 4 + 2], ms[q * 4 + 3]);
            *reinterpret_cast<float4*>(prw + q * 4) = rq;
            *reinterpret_cast<float4*>(pmk + q * 4) = mq;
        }
    }
}

extern "C" void kernel_launch(void* const* d_in, const int* in_sizes, int n_in,
                              void* d_out, int out_size, void* d_ws, size_t ws_size,
                              hipStream_t stream) {
    const float* H     = (const float*)d_in[0];
    const float* Wm    = (const float*)d_in[1];
    const float* gates = (const float*)d_in[2];
    const int N = in_sizes[0] / CDIM;     // 16384 tokens

    unsigned short* whi = (unsigned short*)d_ws;
    unsigned short* wlo = whi + (size_t)EDIM * CDIM;

    float* out_rw = (float*)d_out;
    float* out_lg = out_rw + (size_t)N * EDIM;
    float* out_mk = out_lg + (size_t)N * EDIM;

    hipLaunchKernelGGL(prep_w, dim3(EDIM), dim3(256), 0, stream, Wm, whi, wlo);
    hipLaunchKernelGGL(gating_main, dim3(N / BM), dim3(128), 0, stream,
                       H, whi, wlo, gates, out_rw, out_lg, out_mk);
}